// Round 7
// baseline (432.256 us; speedup 1.0000x reference)
//
#include <hip/hip_runtime.h>

// Problem constants (match reference)
#define NQ     22
#define TARGET 10
#define BATCH  16
#define NOPS   8

constexpr int A      = 1 << TARGET;             // 1024 (outer dim)
constexpr int C      = 1 << (NQ - TARGET - 1);  // 2048 (inner dim)
constexpr int INNER  = C * BATCH;               // 32768 floats between the j=0/j=1 halves
constexpr int INNER4 = INNER / 4;               // 8192 float4s
constexpr int TOTAL4 = A * INNER4;              // 8,388,608 vec4 pair-iterations

__global__ __launch_bounds__(256)
void apply_composed_gate(const float* __restrict__ state,
                         const float* __restrict__ gates,
                         float* __restrict__ out) {
    // ---- compose U = G7 @ G6 @ ... @ G0 per batch element into LDS ----
    __shared__ float u[4][BATCH];   // rows: u00, u01, u10, u11
    const int t = threadIdx.x;
    if (t < BATCH) {
        const int b = t;
        const float* g = gates + (NOPS - 1) * 4 * BATCH;
        float u00 = g[0 * BATCH + b], u01 = g[1 * BATCH + b];
        float u10 = g[2 * BATCH + b], u11 = g[3 * BATCH + b];
        for (int k = NOPS - 2; k >= 0; --k) {
            const float* gk = gates + k * 4 * BATCH;
            const float g00 = gk[0 * BATCH + b], g01 = gk[1 * BATCH + b];
            const float g10 = gk[2 * BATCH + b], g11 = gk[3 * BATCH + b];
            const float n00 = u00 * g00 + u01 * g10;
            const float n01 = u00 * g01 + u01 * g11;
            const float n10 = u10 * g00 + u11 * g10;
            const float n11 = u10 * g01 + u11 * g11;
            u00 = n00; u01 = n01; u10 = n10; u11 = n11;
        }
        u[0][b] = u00; u[1][b] = u01; u[2][b] = u10; u[3][b] = u11;
    }
    __syncthreads();

    // ---- vectorized apply ----
    const int idx0   = blockIdx.x * blockDim.x + t;
    const int stride = gridDim.x * blockDim.x;      // multiple of 4 -> b0 invariant

    // Each float4 covers 4 consecutive batch lanes; which 4 depends only on idx&3.
    const int b0 = (idx0 & 3) * 4;
    const float4 U00 = *(const float4*)&u[0][b0];
    const float4 U01 = *(const float4*)&u[1][b0];
    const float4 U10 = *(const float4*)&u[2][b0];
    const float4 U11 = *(const float4*)&u[3][b0];

    const float4* __restrict__ s4 = (const float4*)state;
    float4* __restrict__ o4 = (float4*)out;

    for (int p = idx0; p < TOTAL4; p += stride) {
        // p = aa * INNER4 + r ; base = aa * 2*INNER4 + r = p + (p & ~(INNER4-1))
        const int base = p + (p & ~(INNER4 - 1));
        const float4 s0 = s4[base];
        const float4 s1 = s4[base + INNER4];
        float4 o0, o1;
        o0.x = U00.x * s0.x + U01.x * s1.x;
        o0.y = U00.y * s0.y + U01.y * s1.y;
        o0.z = U00.z * s0.z + U01.z * s1.z;
        o0.w = U00.w * s0.w + U01.w * s1.w;
        o1.x = U10.x * s0.x + U11.x * s1.x;
        o1.y = U10.y * s0.y + U11.y * s1.y;
        o1.z = U10.z * s0.z + U11.z * s1.z;
        o1.w = U10.w * s0.w + U11.w * s1.w;
        o4[base]          = o0;
        o4[base + INNER4] = o1;
    }
}

extern "C" void kernel_launch(void* const* d_in, const int* in_sizes, int n_in,
                              void* d_out, int out_size, void* d_ws, size_t ws_size,
                              hipStream_t stream) {
    const float* state = (const float*)d_in[0];
    const float* gates = (const float*)d_in[1];
    float* out = (float*)d_out;

    const int block = 256;
    const int grid  = 2048;   // 16 grid-stride iterations per thread
    apply_composed_gate<<<grid, block, 0, stream>>>(state, gates, out);
}